// Round 7
// baseline (228.129 us; speedup 1.0000x reference)
//
#include <hip/hip_runtime.h>
#include <hip/hip_cooperative_groups.h>
#include <math.h>

namespace cg = cooperative_groups;

#define TAU_INV (1.0f / 0.07f)
#define KSEL 50
#define KPAD 64      // zero-padded rows 50..63: dot=0 -> exp=1 -> subtract 14
#define NPIX 8192
#define CCH 128
#define HWSZ 4096
#define NCLS 4
#define EPSL 1e-8f
#define NBINS 1026
#define PXT 16       // pixels per loss chunk
#define SROW 132     // LDS row stride in floats

// ---------------------------------------------------------------------------
// Shared-memory union: phases are separated by grid.sync / kernel boundaries.
// Max member ~50.8 KB -> 3 blocks/CU -> 768 co-resident >= 512 grid blocks.
// ---------------------------------------------------------------------------
union SharedU {
    struct {
        float tile[CCH][65];
        float partial[4][64];
        float invn[64];
    } a;
    struct {
        unsigned hist[NBINS];
        unsigned coarse[33];
        unsigned long long cand[2048];
        unsigned above_cnt, cand_cnt, bucket_cnt;
        int sB, sc0;
    } b;
    struct {
        float Sl[KPAD * SROW];   // 33792 B
        float Xl[PXT * SROW];    //  8448 B
        float Pl[PXT * SROW];    //  8448 B
        float bsum[4];
    } cst;
};

// ---------------------------------------------------------------------------
// Phase A: blocks 0..383 norm+transpose (3 tensors x 128 chunks);
// blocks 384..391 seg (argmax + max softmax prob); block 0 zeroes out.
// ---------------------------------------------------------------------------
__device__ void phaseA(SharedU* sh, int blk, int t,
                       const float* __restrict__ input,
                       const float* __restrict__ positive,
                       const float* __restrict__ negative,
                       const float* __restrict__ ilog,
                       const float* __restrict__ nlog,
                       float* __restrict__ ni, float* __restrict__ np_,
                       float* __restrict__ nn,
                       int* __restrict__ seg_in, int* __restrict__ seg_neg,
                       float* __restrict__ neg_prob, float* __restrict__ out) {
    if (blk == 0 && t == 0) out[0] = 0.0f;

    if (blk < 384) {
        int tensor = blk >> 7, chunk = blk & 127;
        const float* src = (tensor == 0) ? input : (tensor == 1) ? positive : negative;
        float*       dst = (tensor == 0) ? ni    : (tensor == 1) ? np_      : nn;

        int n0 = chunk * 64;
        int b = n0 >> 12, hw0 = n0 & (HWSZ - 1);
        const float* base = src + (size_t)b * CCH * HWSZ + hw0;

        #pragma unroll
        for (int i = 0; i < 8; ++i) {
            int lin = t + i * 256;
            int c = lin >> 4, hwq = (lin & 15) * 4;
            float4 v = *(const float4*)&base[(size_t)c * HWSZ + hwq];
            sh->a.tile[c][hwq + 0] = v.x; sh->a.tile[c][hwq + 1] = v.y;
            sh->a.tile[c][hwq + 2] = v.z; sh->a.tile[c][hwq + 3] = v.w;
        }
        __syncthreads();

        int nof = t & 63, part = t >> 6;
        float s = 0.f;
        #pragma unroll
        for (int j = 0; j < 32; ++j) {
            float v = sh->a.tile[part * 32 + j][nof];
            s += v * v;
        }
        sh->a.partial[part][nof] = s;
        __syncthreads();
        if (t < 64) {
            float tot = sh->a.partial[0][t] + sh->a.partial[1][t] +
                        sh->a.partial[2][t] + sh->a.partial[3][t];
            sh->a.invn[t] = 1.0f / fmaxf(sqrtf(tot), 1e-12f);
        }
        __syncthreads();

        #pragma unroll
        for (int i = 0; i < 8; ++i) {
            int lin = t + i * 256;
            int nf = lin >> 5, cq = (lin & 31) * 4;
            float inv = sh->a.invn[nf];
            float4 o;
            o.x = sh->a.tile[cq + 0][nf] * inv;
            o.y = sh->a.tile[cq + 1][nf] * inv;
            o.z = sh->a.tile[cq + 2][nf] * inv;
            o.w = sh->a.tile[cq + 3][nf] * inv;
            *(float4*)&dst[(size_t)(n0 + nf) * CCH + cq] = o;
        }
    } else if (blk < 392) {
        int n0 = ((blk - 384) * 256 + t) * 4;
        int b = n0 >> 12, hw = n0 & (HWSZ - 1);

        const float* pi = ilog + (size_t)b * NCLS * HWSZ + hw;
        float4 a0 = *(const float4*)&pi[0];
        float4 a1 = *(const float4*)&pi[HWSZ];
        float4 a2 = *(const float4*)&pi[2 * HWSZ];
        float4 a3 = *(const float4*)&pi[3 * HWSZ];
        const float* pn = nlog + (size_t)b * NCLS * HWSZ + hw;
        float4 b0 = *(const float4*)&pn[0];
        float4 b1 = *(const float4*)&pn[HWSZ];
        float4 b2 = *(const float4*)&pn[2 * HWSZ];
        float4 b3 = *(const float4*)&pn[3 * HWSZ];

        int4 si4, sn4; float4 npb;
        const float* A0 = (const float*)&a0; const float* A1 = (const float*)&a1;
        const float* A2 = (const float*)&a2; const float* A3 = (const float*)&a3;
        const float* B0 = (const float*)&b0; const float* B1 = (const float*)&b1;
        const float* B2 = (const float*)&b2; const float* B3 = (const float*)&b3;
        int* SI = (int*)&si4; int* SN = (int*)&sn4; float* NP = (float*)&npb;
        #pragma unroll
        for (int j = 0; j < 4; ++j) {
            float l0 = A0[j], l1 = A1[j], l2 = A2[j], l3 = A3[j];
            int bi = 0; float bv = l0;
            if (l1 > bv) { bv = l1; bi = 1; }
            if (l2 > bv) { bv = l2; bi = 2; }
            if (l3 > bv) { bv = l3; bi = 3; }
            SI[j] = bi;
            float m0 = B0[j], m1 = B1[j], m2 = B2[j], m3 = B3[j];
            int ci = 0; float cv = m0;
            if (m1 > cv) { cv = m1; ci = 1; }
            if (m2 > cv) { cv = m2; ci = 2; }
            if (m3 > cv) { cv = m3; ci = 3; }
            SN[j] = ci;
            float s = expf(m0 - cv) + expf(m1 - cv) + expf(m2 - cv) + expf(m3 - cv);
            NP[j] = 1.0f / s;
        }
        *(int4*)&seg_in[n0] = si4;
        *(int4*)&seg_neg[n0] = sn4;
        *(float4*)&neg_prob[n0] = npb;
    }
}

// ---------------------------------------------------------------------------
// Phase B: blocks 0..3 (c = blk): top-50 histogram select + bucketing.
// 256 threads x 32 elements.  Selected SET == jax.lax.top_k set (tie ->
// lowest index).  Keys reloaded in phase 3 (keeps VGPR low).
// ---------------------------------------------------------------------------
__device__ void phaseB(SharedU* sh, int c, int t,
                       const int* __restrict__ seg_in,
                       const int* __restrict__ seg_neg,
                       const float* __restrict__ neg_prob,
                       int* __restrict__ topk, int* __restrict__ perm,
                       int* __restrict__ cnt) {
    for (int i = t; i < NBINS; i += 256) sh->b.hist[i] = 0;
    if (t < 33) sh->b.coarse[t] = 0;
    if (t == 0) { sh->b.above_cnt = 0; sh->b.cand_cnt = 0; sh->b.bucket_cnt = 0; }
    __syncthreads();

    // Phase 1: histogram + same-class pixel bucketing
    #pragma unroll
    for (int s = 0; s < 8; ++s) {
        int i4 = (t + s * 256) * 4;
        int4 sn = *(const int4*)&seg_neg[i4];
        int4 sg = *(const int4*)&seg_in[i4];
        float4 npv = *(const float4*)&neg_prob[i4];
        const int* SN = (const int*)&sn;
        const int* SG = (const int*)&sg;
        const float* NP = (const float*)&npv;
        #pragma unroll
        for (int j = 0; j < 4; ++j) {
            float v = (SN[j] != c) ? NP[j] : 0.0f;
            unsigned key = __float_as_uint(v);
            int bin = (key < 0x3E800000u) ? 0 : (int)(1u + ((key - 0x3E800000u) >> 14));
            atomicAdd(&sh->b.hist[bin], 1u);
            if (SG[j] == c) {
                unsigned p = atomicAdd(&sh->b.bucket_cnt, 1u);
                perm[c * NPIX + p] = i4 + j;
            }
        }
    }
    __syncthreads();
    if (t == 0) cnt[c] = (int)sh->b.bucket_cnt;

    for (int i = t; i < NBINS; i += 256) atomicAdd(&sh->b.coarse[i >> 5], sh->b.hist[i]);
    __syncthreads();

    if (t == 0) {
        unsigned cum = 0; int j = 32;
        for (; j > 0; --j) {
            unsigned h = sh->b.coarse[j];
            if (cum + h >= KSEL) break;
            cum += h;
        }
        int hi = j * 32 + 31; if (hi > NBINS - 1) hi = NBINS - 1;
        int B = 0;
        for (int b = hi; b >= j * 32; --b) {
            unsigned h = sh->b.hist[b];
            if (cum + h >= KSEL) { B = b; break; }
            cum += h;
        }
        sh->b.sB = B; sh->b.sc0 = (int)cum;
    }
    __syncthreads();
    int B = sh->b.sB, c0 = sh->b.sc0;

    // Phase 3: reload, emit definite winners, collect boundary candidates
    #pragma unroll
    for (int s = 0; s < 8; ++s) {
        int i4 = (t + s * 256) * 4;
        int4 sn = *(const int4*)&seg_neg[i4];
        float4 npv = *(const float4*)&neg_prob[i4];
        const int* SN = (const int*)&sn;
        const float* NP = (const float*)&npv;
        #pragma unroll
        for (int j = 0; j < 4; ++j) {
            float v = (SN[j] != c) ? NP[j] : 0.0f;
            unsigned key = __float_as_uint(v);
            int bin = (key < 0x3E800000u) ? 0 : (int)(1u + ((key - 0x3E800000u) >> 14));
            if (bin > B) {
                unsigned pos = atomicAdd(&sh->b.above_cnt, 1u);
                topk[c * KSEL + pos] = i4 + j;
            } else if (bin == B) {
                unsigned jj = atomicAdd(&sh->b.cand_cnt, 1u);
                if (jj < 2048)
                    sh->b.cand[jj] = ((unsigned long long)key << 32) |
                                     (unsigned long long)(0xFFFFFFFFu - (unsigned)(i4 + j));
            }
        }
    }
    __syncthreads();

    int m = KSEL - c0;
    int cb = (int)sh->b.cand_cnt; if (cb > 2048) cb = 2048;
    if (t < 64) {
        for (int r = 0; r < m; ++r) {
            unsigned long long best = 0;
            for (int j = t; j < cb; j += 64) {
                unsigned long long v = sh->b.cand[j];
                if (v > best) best = v;
            }
            #pragma unroll
            for (int off = 32; off; off >>= 1) {
                unsigned long long o = __shfl_xor(best, off);
                if (o > best) best = o;
            }
            if (t == 0) topk[c * KSEL + c0 + r] = (int)(0xFFFFFFFFu - (unsigned)(best & 0xFFFFFFFFull));
            for (int j = t; j < cb; j += 64)
                if (sh->b.cand[j] == best) sh->b.cand[j] = 0;
        }
    }
}

// ---------------------------------------------------------------------------
// Phase C: all blocks.  c = blk & 3, chunk base = blk >> 2; S staged once per
// block, chunk loop covers data-dependent class counts.  Thread (ktid,pxid)
// owns 4 S-rows x 1 pixel; dots accumulate fully in registers.
// ---------------------------------------------------------------------------
__device__ void phaseC(SharedU* sh, int blk, int t,
                       const float* __restrict__ ni,
                       const float* __restrict__ npos,
                       const float* __restrict__ nn,
                       const int* __restrict__ topk,
                       const int* __restrict__ perm,
                       const int* __restrict__ cnt,
                       float* __restrict__ out) {
    int c = blk & 3;
    int count = cnt[c];
    int start0 = (blk >> 2) * PXT;
    if (start0 >= count) return;

    // stage S once: 4 threads per row, 32 ch each
    {
        int row = t >> 2;
        int ch0 = (t & 3) * 32;
        float* dst = &sh->cst.Sl[row * SROW + ch0];
        if (row < KSEL) {
            const float* src = nn + (size_t)topk[c * KSEL + row] * CCH + ch0;
            #pragma unroll
            for (int i = 0; i < 8; ++i)
                ((float4*)dst)[i] = ((const float4*)src)[i];
        } else {
            float4 z = make_float4(0.f, 0.f, 0.f, 0.f);
            #pragma unroll
            for (int i = 0; i < 8; ++i)
                ((float4*)dst)[i] = z;
        }
    }

    int ktid = t & 15, pxid = t >> 4;
    float vtot = 0.f;

    for (int start = start0; start < count; start += 128 * PXT) {
        // stage X, P: 16 threads per pixel, 8 ch each
        {
            int row = t >> 4;
            int slot = start + row;
            int px = perm[c * NPIX + ((slot < count) ? slot : start)];
            int ch0 = (t & 15) * 8;
            const float* sx = ni + (size_t)px * CCH + ch0;
            const float* sp = npos + (size_t)px * CCH + ch0;
            float* dx = &sh->cst.Xl[row * SROW + ch0];
            float* dp = &sh->cst.Pl[row * SROW + ch0];
            ((float4*)dx)[0] = ((const float4*)sx)[0];
            ((float4*)dx)[1] = ((const float4*)sx)[1];
            ((float4*)dp)[0] = ((const float4*)sp)[0];
            ((float4*)dp)[1] = ((const float4*)sp)[1];
        }
        __syncthreads();

        float acc_i[4] = {0.f, 0.f, 0.f, 0.f};
        float acc_p[4] = {0.f, 0.f, 0.f, 0.f};
        float ps = 0.f;
        const float* Xr = &sh->cst.Xl[pxid * SROW];
        const float* Pr = &sh->cst.Pl[pxid * SROW];

        #pragma unroll 4
        for (int ch = 0; ch < CCH; ch += 4) {
            float4 xv = *(const float4*)&Xr[ch];
            float4 pv = *(const float4*)&Pr[ch];
            ps += xv.x * pv.x + xv.y * pv.y + xv.z * pv.z + xv.w * pv.w;
            #pragma unroll
            for (int r = 0; r < 4; ++r) {
                float4 sv = *(const float4*)&sh->cst.Sl[(ktid + r * 16) * SROW + ch];
                acc_i[r] += sv.x * xv.x + sv.y * xv.y + sv.z * xv.z + sv.w * xv.w;
                acc_p[r] += sv.x * pv.x + sv.y * pv.y + sv.z * pv.z + sv.w * pv.w;
            }
        }

        float si = 0.f, spp = 0.f;
        #pragma unroll
        for (int r = 0; r < 4; ++r) {
            si  += expf(acc_i[r] * TAU_INV);
            spp += expf(acc_p[r] * TAU_INV);
        }
        #pragma unroll
        for (int off = 1; off < 16; off <<= 1) {
            si  += __shfl_xor(si, off);
            spp += __shfl_xor(spp, off);
        }

        if (ktid == 0 && (start + pxid) < count) {
            si  -= (float)(KPAD - KSEL);
            spp -= (float)(KPAD - KSEL);
            float nom = expf(ps * TAU_INV);
            float li = -logf(nom / (si + nom + EPSL));
            float lp = -logf(nom / (spp + nom + EPSL));
            vtot += (li + lp) * (1.0f / (float)NPIX);
        }
        __syncthreads();   // X/P fully consumed before next staging
    }

    float v = vtot;
    v += __shfl_xor(v, 1);   // no-op (only ktid==0 nonzero) kept minimal:
    v = vtot;
    v += __shfl_xor(v, 16);
    v += __shfl_xor(v, 32);
    int w = t >> 6;
    if ((t & 63) == 0) sh->cst.bsum[w] = v;
    __syncthreads();
    if (t == 0) {
        float s = sh->cst.bsum[0] + sh->cst.bsum[1] + sh->cst.bsum[2] + sh->cst.bsum[3];
        atomicAdd(out, s);
    }
}

// ---------------------------------------------------------------------------
// Fused cooperative kernel (512 blocks x 256 threads).
// ---------------------------------------------------------------------------
__global__ void __launch_bounds__(256) fused_kernel(
        const float* input, const float* positive, const float* negative,
        const float* ilog, const float* nlog,
        float* ni, float* np_, float* nn,
        int* seg_in, int* seg_neg, float* neg_prob,
        int* topk, int* perm, int* cnt, float* out) {
    __shared__ SharedU sh;
    int blk = blockIdx.x, t = threadIdx.x;
    cg::grid_group grid = cg::this_grid();

    phaseA(&sh, blk, t, input, positive, negative, ilog, nlog,
           ni, np_, nn, seg_in, seg_neg, neg_prob, out);
    grid.sync();
    if (blk < NCLS)
        phaseB(&sh, blk, t, seg_in, seg_neg, neg_prob, topk, perm, cnt);
    grid.sync();
    phaseC(&sh, blk, t, ni, np_, nn, topk, perm, cnt, out);
}

// ---- standalone fallbacks (same device code, 3 launches) -------------------
__global__ void __launch_bounds__(256) megaA_kernel(
        const float* input, const float* positive, const float* negative,
        const float* ilog, const float* nlog,
        float* ni, float* np_, float* nn,
        int* seg_in, int* seg_neg, float* neg_prob, float* out) {
    __shared__ SharedU sh;
    phaseA(&sh, blockIdx.x, threadIdx.x, input, positive, negative, ilog, nlog,
           ni, np_, nn, seg_in, seg_neg, neg_prob, out);
}
__global__ void __launch_bounds__(256) topkB_kernel(
        const int* seg_in, const int* seg_neg, const float* neg_prob,
        int* topk, int* perm, int* cnt) {
    __shared__ SharedU sh;
    phaseB(&sh, blockIdx.x, threadIdx.x, seg_in, seg_neg, neg_prob, topk, perm, cnt);
}
__global__ void __launch_bounds__(256) lossC_kernel(
        const float* ni, const float* npos, const float* nn,
        const int* topk, const int* perm, const int* cnt, float* out) {
    __shared__ SharedU sh;
    phaseC(&sh, blockIdx.x, threadIdx.x, ni, npos, nn, topk, perm, cnt, out);
}

// ---------------------------------------------------------------------------
extern "C" void kernel_launch(void* const* d_in, const int* in_sizes, int n_in,
                              void* d_out, int out_size, void* d_ws, size_t ws_size,
                              hipStream_t stream) {
    const float* input      = (const float*)d_in[0];
    const float* positive   = (const float*)d_in[1];
    const float* negative   = (const float*)d_in[2];
    const float* in_logits  = (const float*)d_in[3];
    const float* neg_logits = (const float*)d_in[4];
    float* out = (float*)d_out;

    float* ws  = (float*)d_ws;
    float* ni  = ws;                               // [N*C]
    float* np_ = ws + 1048576;                     // [N*C]
    float* nn  = ws + 2097152;                     // [N*C]
    int*   seg_in   = (int*)(ws + 3145728);        // [N]
    int*   seg_neg  = seg_in + NPIX;               // [N]
    float* neg_prob = (float*)(seg_neg + NPIX);    // [N]
    int*   topk     = (int*)(neg_prob + NPIX);     // [4*50] (pad 256)
    int*   cnt      = topk + 256;                  // [4] (pad 64)
    int*   perm     = cnt + 64;                    // [4*N]

    void* args[] = {
        (void*)&input, (void*)&positive, (void*)&negative,
        (void*)&in_logits, (void*)&neg_logits,
        (void*)&ni, (void*)&np_, (void*)&nn,
        (void*)&seg_in, (void*)&seg_neg, (void*)&neg_prob,
        (void*)&topk, (void*)&perm, (void*)&cnt, (void*)&out
    };
    hipError_t e = hipLaunchCooperativeKernel((const void*)fused_kernel,
                                              dim3(512), dim3(256),
                                              args, 0, stream);
    if (e != hipSuccess) {
        // fallback: same phases as 3 stream-ordered launches
        megaA_kernel<<<392, 256, 0, stream>>>(input, positive, negative,
                                              in_logits, neg_logits,
                                              ni, np_, nn, seg_in, seg_neg,
                                              neg_prob, out);
        topkB_kernel<<<NCLS, 256, 0, stream>>>(seg_in, seg_neg, neg_prob,
                                               topk, perm, cnt);
        lossC_kernel<<<512, 256, 0, stream>>>(ni, np_, nn, topk, perm, cnt, out);
    }
}

// Round 8
// 99.730 us; speedup vs baseline: 2.2875x; 2.2875x over previous
//
#include <hip/hip_runtime.h>
#include <math.h>

#define TAU_INV (1.0f / 0.07f)
#define KSEL 50
#define KPAD 64      // zero-padded rows 50..63: dot=0 -> exp=1 -> subtract 14
#define NPIX 8192
#define CCH 128
#define HWSZ 4096
#define NCLS 4
#define EPSL 1e-8f
#define NBINS 1026
#define PXT 32       // pixels per loss block
#define SROW 132     // LDS row stride in floats

// ---------------------------------------------------------------------------
// Kernel 1 (mega): blocks 0..383 = L2-normalize+transpose the 3 tensors
// (float4 global traffic both directions); blocks 384..391 = seg path,
// 4 pixels/thread via float4.
// ---------------------------------------------------------------------------
__global__ void __launch_bounds__(256) mega_kernel(
        const float* __restrict__ input, const float* __restrict__ positive,
        const float* __restrict__ negative,
        const float* __restrict__ ilog, const float* __restrict__ nlog,
        float* __restrict__ ni, float* __restrict__ np_, float* __restrict__ nn,
        int* __restrict__ seg_in, int* __restrict__ seg_neg,
        float* __restrict__ neg_prob) {
    __shared__ float tile[CCH][65];   // stride 65
    __shared__ float partial[4][64];
    __shared__ float invn[64];

    int t = threadIdx.x;
    int blk = blockIdx.x;

    if (blk < 384) {
        int tensor = blk >> 7, chunk = blk & 127;
        const float* src = (tensor == 0) ? input : (tensor == 1) ? positive : negative;
        float*       dst = (tensor == 0) ? ni    : (tensor == 1) ? np_      : nn;

        int n0 = chunk * 64;
        int b = n0 >> 12, hw0 = n0 & (HWSZ - 1);
        const float* base = src + (size_t)b * CCH * HWSZ + hw0;

        #pragma unroll
        for (int i = 0; i < 8; ++i) {
            int lin = t + i * 256;
            int c = lin >> 4, hwq = (lin & 15) * 4;
            float4 v = *(const float4*)&base[(size_t)c * HWSZ + hwq];
            tile[c][hwq + 0] = v.x; tile[c][hwq + 1] = v.y;
            tile[c][hwq + 2] = v.z; tile[c][hwq + 3] = v.w;
        }
        __syncthreads();

        int nof = t & 63, part = t >> 6;
        float s = 0.f;
        #pragma unroll
        for (int j = 0; j < 32; ++j) {
            float v = tile[part * 32 + j][nof];
            s += v * v;
        }
        partial[part][nof] = s;
        __syncthreads();
        if (t < 64) {
            float tot = partial[0][t] + partial[1][t] + partial[2][t] + partial[3][t];
            invn[t] = 1.0f / fmaxf(sqrtf(tot), 1e-12f);
        }
        __syncthreads();

        #pragma unroll
        for (int i = 0; i < 8; ++i) {
            int lin = t + i * 256;
            int nf = lin >> 5, cq = (lin & 31) * 4;
            float inv = invn[nf];
            float4 o;
            o.x = tile[cq + 0][nf] * inv;
            o.y = tile[cq + 1][nf] * inv;
            o.z = tile[cq + 2][nf] * inv;
            o.w = tile[cq + 3][nf] * inv;
            *(float4*)&dst[(size_t)(n0 + nf) * CCH + cq] = o;
        }
    } else {
        int n0 = ((blk - 384) * 256 + t) * 4;
        int b = n0 >> 12, hw = n0 & (HWSZ - 1);

        const float* pi = ilog + (size_t)b * NCLS * HWSZ + hw;
        float4 a0 = *(const float4*)&pi[0];
        float4 a1 = *(const float4*)&pi[HWSZ];
        float4 a2 = *(const float4*)&pi[2 * HWSZ];
        float4 a3 = *(const float4*)&pi[3 * HWSZ];
        const float* pn = nlog + (size_t)b * NCLS * HWSZ + hw;
        float4 b0 = *(const float4*)&pn[0];
        float4 b1 = *(const float4*)&pn[HWSZ];
        float4 b2 = *(const float4*)&pn[2 * HWSZ];
        float4 b3 = *(const float4*)&pn[3 * HWSZ];

        int4 si4, sn4; float4 npb;
        const float* A0 = (const float*)&a0; const float* A1 = (const float*)&a1;
        const float* A2 = (const float*)&a2; const float* A3 = (const float*)&a3;
        const float* B0 = (const float*)&b0; const float* B1 = (const float*)&b1;
        const float* B2 = (const float*)&b2; const float* B3 = (const float*)&b3;
        int* SI = (int*)&si4; int* SN = (int*)&sn4; float* NP = (float*)&npb;
        #pragma unroll
        for (int j = 0; j < 4; ++j) {
            float l0 = A0[j], l1 = A1[j], l2 = A2[j], l3 = A3[j];
            int bi = 0; float bv = l0;
            if (l1 > bv) { bv = l1; bi = 1; }
            if (l2 > bv) { bv = l2; bi = 2; }
            if (l3 > bv) { bv = l3; bi = 3; }
            SI[j] = bi;
            float m0 = B0[j], m1 = B1[j], m2 = B2[j], m3 = B3[j];
            int ci = 0; float cv = m0;
            if (m1 > cv) { cv = m1; ci = 1; }
            if (m2 > cv) { cv = m2; ci = 2; }
            if (m3 > cv) { cv = m3; ci = 3; }
            SN[j] = ci;
            float s = expf(m0 - cv) + expf(m1 - cv) + expf(m2 - cv) + expf(m3 - cv);
            NP[j] = 1.0f / s;
        }
        *(int4*)&seg_in[n0] = si4;
        *(int4*)&seg_neg[n0] = sn4;
        *(float4*)&neg_prob[n0] = npb;
    }
}

// ---------------------------------------------------------------------------
// Kernel 2: per class c (one block each): top-50 histogram select +
// same-class pixel bucketing + out zeroing.
// ---------------------------------------------------------------------------
__global__ void __launch_bounds__(1024) topk_kernel(
        const int* __restrict__ seg_in, const int* __restrict__ seg_neg,
        const float* __restrict__ neg_prob,
        int* __restrict__ topk, int* __restrict__ perm, int* __restrict__ cnt,
        float* __restrict__ out) {
    __shared__ unsigned hist[NBINS];
    __shared__ unsigned coarse[33];
    __shared__ unsigned long long cand[2048];
    __shared__ unsigned above_cnt, cand_cnt, bucket_cnt;
    __shared__ int sB, sc0;

    int c = blockIdx.x, t = threadIdx.x;
    if (c == 0 && t == 0) out[0] = 0.0f;

    for (int i = t; i < NBINS; i += 1024) hist[i] = 0;
    if (t < 33) coarse[t] = 0;
    if (t == 0) { above_cnt = 0; cand_cnt = 0; bucket_cnt = 0; }
    __syncthreads();

    unsigned keys[8]; int bins[8];
    #pragma unroll
    for (int s = 0; s < 2; ++s) {
        int i4 = (t + s * 1024) * 4;
        int4 sn = *(const int4*)&seg_neg[i4];
        int4 sg = *(const int4*)&seg_in[i4];
        float4 npv = *(const float4*)&neg_prob[i4];
        const int* SN = (const int*)&sn;
        const int* SG = (const int*)&sg;
        const float* NP = (const float*)&npv;
        #pragma unroll
        for (int j = 0; j < 4; ++j) {
            float v = (SN[j] != c) ? NP[j] : 0.0f;
            unsigned key = __float_as_uint(v);
            int bin = (key < 0x3E800000u) ? 0 : (int)(1u + ((key - 0x3E800000u) >> 14));
            keys[s * 4 + j] = key; bins[s * 4 + j] = bin;
            atomicAdd(&hist[bin], 1u);
            if (SG[j] == c) {
                unsigned p = atomicAdd(&bucket_cnt, 1u);
                perm[c * NPIX + p] = i4 + j;
            }
        }
    }
    __syncthreads();
    if (t == 0) cnt[c] = (int)bucket_cnt;

    for (int i = t; i < NBINS; i += 1024) atomicAdd(&coarse[i >> 5], hist[i]);
    __syncthreads();

    if (t == 0) {
        unsigned cum = 0; int j = 32;
        for (; j > 0; --j) {
            unsigned h = coarse[j];
            if (cum + h >= KSEL) break;
            cum += h;
        }
        int hi = j * 32 + 31; if (hi > NBINS - 1) hi = NBINS - 1;
        int B = 0;
        for (int b = hi; b >= j * 32; --b) {
            unsigned h = hist[b];
            if (cum + h >= KSEL) { B = b; break; }
            cum += h;
        }
        sB = B; sc0 = (int)cum;
    }
    __syncthreads();
    int B = sB, c0 = sc0;

    #pragma unroll
    for (int s = 0; s < 8; ++s) {
        int i = (t + (s >> 2) * 1024) * 4 + (s & 3);
        if (bins[s] > B) {
            unsigned pos = atomicAdd(&above_cnt, 1u);
            topk[c * KSEL + pos] = i;
        } else if (bins[s] == B) {
            unsigned j = atomicAdd(&cand_cnt, 1u);
            if (j < 2048)
                cand[j] = ((unsigned long long)keys[s] << 32) |
                          (unsigned long long)(0xFFFFFFFFu - (unsigned)i);
        }
    }
    __syncthreads();

    int m = KSEL - c0;
    int cb = (int)cand_cnt; if (cb > 2048) cb = 2048;
    if (t < 64) {
        for (int r = 0; r < m; ++r) {
            unsigned long long best = 0;
            for (int j = t; j < cb; j += 64) {
                unsigned long long v = cand[j];
                if (v > best) best = v;
            }
            #pragma unroll
            for (int off = 32; off; off >>= 1) {
                unsigned long long o = __shfl_xor(best, off);
                if (o > best) best = o;
            }
            if (t == 0) topk[c * KSEL + c0 + r] = (int)(0xFFFFFFFFu - (unsigned)(best & 0xFFFFFFFFull));
            for (int j = t; j < cb; j += 64)
                if (cand[j] == best) cand[j] = 0;
        }
    }
}

// ---------------------------------------------------------------------------
// Kernel 3: same-class GEMM-style loss.  Block = 32 pixels of one class.
// Thread (ktid 0..7, pxid 0..31) owns 8 k-rows x 1 pixel; dots accumulate in
// registers (no shuffles in inner loop).  Adds (li+lp)/NPIX into d_out.
// ---------------------------------------------------------------------------
__global__ void __launch_bounds__(256) loss_kernel(
        const float* __restrict__ ni, const float* __restrict__ npos,
        const float* __restrict__ nn, const int* __restrict__ topk,
        const int* __restrict__ perm, const int* __restrict__ cnt,
        float* __restrict__ out) {
    __shared__ float Sl[KPAD * SROW];   // 33792 B
    __shared__ float Xl[PXT * SROW];    // 16896 B
    __shared__ float Pl[PXT * SROW];    // 16896 B
    __shared__ float bsum[4];

    int c = blockIdx.y;
    int count = cnt[c];
    int start = blockIdx.x * PXT;
    if (start >= count) return;
    int t = threadIdx.x;

    // stage S: 4 threads per row, 32 ch each
    {
        int row = t >> 2;
        int ch0 = (t & 3) * 32;
        float* dst = &Sl[row * SROW + ch0];
        if (row < KSEL) {
            const float* src = nn + (size_t)topk[c * KSEL + row] * CCH + ch0;
            #pragma unroll
            for (int i = 0; i < 8; ++i)
                ((float4*)dst)[i] = ((const float4*)src)[i];
        } else {
            float4 z = make_float4(0.f, 0.f, 0.f, 0.f);
            #pragma unroll
            for (int i = 0; i < 8; ++i)
                ((float4*)dst)[i] = z;
        }
    }
    // stage X, P: 8 threads per pixel row, 16 ch each
    {
        int row = t >> 3;
        int slot = start + row;
        int px = perm[c * NPIX + ((slot < count) ? slot : start)];
        int ch0 = (t & 7) * 16;
        const float* sx = ni + (size_t)px * CCH + ch0;
        const float* sp = npos + (size_t)px * CCH + ch0;
        float* dx = &Xl[row * SROW + ch0];
        float* dp = &Pl[row * SROW + ch0];
        #pragma unroll
        for (int i = 0; i < 4; ++i) {
            ((float4*)dx)[i] = ((const float4*)sx)[i];
            ((float4*)dp)[i] = ((const float4*)sp)[i];
        }
    }
    __syncthreads();

    int ktid = t & 7, pxid = t >> 3;
    float acc_i[8] = {0.f, 0.f, 0.f, 0.f, 0.f, 0.f, 0.f, 0.f};
    float acc_p[8] = {0.f, 0.f, 0.f, 0.f, 0.f, 0.f, 0.f, 0.f};
    float ps = 0.f;
    const float* Xr = &Xl[pxid * SROW];
    const float* Pr = &Pl[pxid * SROW];

    #pragma unroll 2
    for (int ch = 0; ch < CCH; ch += 4) {
        float4 xv = *(const float4*)&Xr[ch];
        float4 pv = *(const float4*)&Pr[ch];
        ps += xv.x * pv.x + xv.y * pv.y + xv.z * pv.z + xv.w * pv.w;
        #pragma unroll
        for (int r = 0; r < 8; ++r) {
            float4 sv = *(const float4*)&Sl[(ktid + r * 8) * SROW + ch];
            acc_i[r] += sv.x * xv.x + sv.y * xv.y + sv.z * xv.z + sv.w * xv.w;
            acc_p[r] += sv.x * pv.x + sv.y * pv.y + sv.z * pv.z + sv.w * pv.w;
        }
    }

    float si = 0.f, spp = 0.f;
    #pragma unroll
    for (int r = 0; r < 8; ++r) {
        si  += expf(acc_i[r] * TAU_INV);
        spp += expf(acc_p[r] * TAU_INV);
    }
    #pragma unroll
    for (int off = 1; off < 8; off <<= 1) {
        si  += __shfl_xor(si, off);
        spp += __shfl_xor(spp, off);
    }

    float v = 0.f;
    if (ktid == 0 && (start + pxid) < count) {
        si  -= (float)(KPAD - KSEL);   // remove exp(0)=1 of the 14 zero rows
        spp -= (float)(KPAD - KSEL);
        float nom = expf(ps * TAU_INV);
        float li = -logf(nom / (si + nom + EPSL));
        float lp = -logf(nom / (spp + nom + EPSL));
        v = (li + lp) * (1.0f / (float)NPIX);
    }
    v += __shfl_xor(v, 8);
    v += __shfl_xor(v, 16);
    v += __shfl_xor(v, 32);
    int w = t >> 6;
    if ((t & 63) == 0) bsum[w] = v;
    __syncthreads();
    if (t == 0) atomicAdd(out, bsum[0] + bsum[1] + bsum[2] + bsum[3]);
}

// ---------------------------------------------------------------------------
extern "C" void kernel_launch(void* const* d_in, const int* in_sizes, int n_in,
                              void* d_out, int out_size, void* d_ws, size_t ws_size,
                              hipStream_t stream) {
    const float* input      = (const float*)d_in[0];
    const float* positive   = (const float*)d_in[1];
    const float* negative   = (const float*)d_in[2];
    const float* in_logits  = (const float*)d_in[3];
    const float* neg_logits = (const float*)d_in[4];
    float* out = (float*)d_out;

    float* ws  = (float*)d_ws;
    float* ni  = ws;                               // [N*C]
    float* np_ = ws + 1048576;                     // [N*C]
    float* nn  = ws + 2097152;                     // [N*C]
    int*   seg_in   = (int*)(ws + 3145728);        // [N]
    int*   seg_neg  = seg_in + NPIX;               // [N]
    float* neg_prob = (float*)(seg_neg + NPIX);    // [N]
    int*   topk     = (int*)(neg_prob + NPIX);     // [4*50] (pad 256)
    int*   cnt      = topk + 256;                  // [4] (pad 64)
    int*   perm     = cnt + 64;                    // [4*N]

    mega_kernel<<<392, 256, 0, stream>>>(input, positive, negative,
                                         in_logits, neg_logits,
                                         ni, np_, nn, seg_in, seg_neg, neg_prob);
    topk_kernel<<<NCLS, 1024, 0, stream>>>(seg_in, seg_neg, neg_prob,
                                           topk, perm, cnt, out);
    dim3 lgrid(NPIX / PXT, NCLS);
    loss_kernel<<<lgrid, 256, 0, stream>>>(ni, np_, nn, topk, perm, cnt, out);
}